// Round 2
// baseline (1000.720 us; speedup 1.0000x reference)
//
#include <hip/hip_runtime.h>

#define FD 128   // feature dim (D == H == 128)

// ---------------- degree / dinv / CSR build ----------------

__global__ void k_deg(const int* __restrict__ dst, int* __restrict__ deg, int E) {
  int e = blockIdx.x * blockDim.x + threadIdx.x;
  if (e < E) atomicAdd(&deg[dst[e]], 1);
}

__global__ void k_dinv(const int* __restrict__ deg, float* __restrict__ dinv, int n) {
  int i = blockIdx.x * blockDim.x + threadIdx.x;
  if (i < n) dinv[i] = rsqrtf((float)(deg[i] + 1));  // +1 = self-loop
}

// single-block exclusive scan of in-degrees -> row_ptr (+ cursor copy)
__global__ __launch_bounds__(1024) void k_scan(const int* __restrict__ deg,
                                               int* __restrict__ row_ptr,
                                               int* __restrict__ cursor, int n) {
  __shared__ int part[1024];
  const int t = threadIdx.x;
  const int C = (n + 1023) >> 10;
  const int lo = t * C;
  const int hi = min(lo + C, n);
  int sum = 0;
  for (int i = lo; i < hi; ++i) sum += deg[i];
  part[t] = sum;
  __syncthreads();
  for (int off = 1; off < 1024; off <<= 1) {
    int v = (t >= off) ? part[t - off] : 0;
    __syncthreads();
    part[t] += v;
    __syncthreads();
  }
  int run = (t == 0) ? 0 : part[t - 1];
  for (int i = lo; i < hi; ++i) {
    row_ptr[i] = run;
    cursor[i]  = run;
    run += deg[i];
  }
  if (t == 1023) row_ptr[n] = part[1023];
}

__global__ void k_fill(const int* __restrict__ src, const int* __restrict__ dst,
                       const float* __restrict__ dinv, int* __restrict__ cursor,
                       int* __restrict__ csr_src, float* __restrict__ csr_coef, int E) {
  int e = blockIdx.x * blockDim.x + threadIdx.x;
  if (e < E) {
    int s = src[e], d = dst[e];
    int pos = atomicAdd(&cursor[d], 1);
    csr_src[pos]  = s;
    csr_coef[pos] = dinv[s] * dinv[d];
  }
}

// ---------------- f32 GEMM: out[r][c0+c] = sum_k A[r][k]*W[k][c0+c] (+bias) ----------------
// 64 rows x 64 cols per block, 256 threads, K=128 staged in two 64-row halves of W.

__global__ __launch_bounds__(256) void k_gemm(const float* __restrict__ A,
                                              const float* __restrict__ W, int ldw,
                                              const float* __restrict__ bias,
                                              float* __restrict__ out, int ldo, int nrows) {
  __shared__ float Ws[64 * 64];
  __shared__ float xs[64][129];   // bank = (r + k) % 32 -> conflict-free column reads
  const int t  = threadIdx.x;
  const int c0 = blockIdx.y * 64;
  const int r0 = blockIdx.x * 64;

  // stage x tile (64 rows x 128 k), zero-pad OOB rows
  for (int i = t; i < 64 * 32; i += 256) {
    int r  = i >> 5;
    int k4 = (i & 31) << 2;
    int row = r0 + r;
    float4 v = make_float4(0.f, 0.f, 0.f, 0.f);
    if (row < nrows) v = *reinterpret_cast<const float4*>(&A[(size_t)row * FD + k4]);
    xs[r][k4 + 0] = v.x; xs[r][k4 + 1] = v.y; xs[r][k4 + 2] = v.z; xs[r][k4 + 3] = v.w;
  }

  const int r  = t & 31;
  const int cb = (t >> 5) << 3;   // 8 col-groups of 8 cols
  float acc0[8], acc1[8];
#pragma unroll
  for (int j = 0; j < 8; ++j) {
    float bz = bias ? bias[c0 + cb + j] : 0.f;
    acc0[j] = bz; acc1[j] = bz;
  }

  for (int half = 0; half < 2; ++half) {
    __syncthreads();   // protect Ws reuse (and xs readiness on first pass)
    // stage W rows [half*64, half*64+64) x 64 cols
    for (int i = t; i < 64 * 16; i += 256) {
      int k  = i >> 4;
      int c4 = (i & 15) << 2;
      *reinterpret_cast<float4*>(&Ws[k * 64 + c4]) =
          *reinterpret_cast<const float4*>(&W[(size_t)(half * 64 + k) * ldw + c0 + c4]);
    }
    __syncthreads();
    const int kbase = half * 64;
#pragma unroll 8
    for (int k = 0; k < 64; ++k) {
      float x0 = xs[r][kbase + k];
      float x1 = xs[r + 32][kbase + k];
      const float4 w0 = *reinterpret_cast<const float4*>(&Ws[k * 64 + cb]);
      const float4 w1 = *reinterpret_cast<const float4*>(&Ws[k * 64 + cb + 4]);
      acc0[0] += x0 * w0.x; acc0[1] += x0 * w0.y; acc0[2] += x0 * w0.z; acc0[3] += x0 * w0.w;
      acc0[4] += x0 * w1.x; acc0[5] += x0 * w1.y; acc0[6] += x0 * w1.z; acc0[7] += x0 * w1.w;
      acc1[0] += x1 * w0.x; acc1[1] += x1 * w0.y; acc1[2] += x1 * w0.z; acc1[3] += x1 * w0.w;
      acc1[4] += x1 * w1.x; acc1[5] += x1 * w1.y; acc1[6] += x1 * w1.z; acc1[7] += x1 * w1.w;
    }
  }

  const int row0 = r0 + r, row1 = r0 + r + 32;
  if (row0 < nrows) {
    float* o = &out[(size_t)row0 * ldo + c0 + cb];
    *reinterpret_cast<float4*>(o)     = make_float4(acc0[0], acc0[1], acc0[2], acc0[3]);
    *reinterpret_cast<float4*>(o + 4) = make_float4(acc0[4], acc0[5], acc0[6], acc0[7]);
  }
  if (row1 < nrows) {
    float* o = &out[(size_t)row1 * ldo + c0 + cb];
    *reinterpret_cast<float4*>(o)     = make_float4(acc1[0], acc1[1], acc1[2], acc1[3]);
    *reinterpret_cast<float4*>(o + 4) = make_float4(acc1[4], acc1[5], acc1[6], acc1[7]);
  }
}

// ---------------- aggregation: out[n] = relu( sum_in h[s]*coef + h[n]*dinv^2 + b ) ----------------
// one 64-lane wave per node, float2 per lane; 4 nodes per 256-thread block

__global__ __launch_bounds__(256) void k_agg(const float* __restrict__ h,
                                             const int* __restrict__ row_ptr,
                                             const int* __restrict__ csr_src,
                                             const float* __restrict__ csr_coef,
                                             const float* __restrict__ dinv,
                                             const float* __restrict__ bias,
                                             float* __restrict__ out, int n) {
  const int node = blockIdx.x * 4 + (threadIdx.x >> 6);
  if (node >= n) return;
  const int f2 = (threadIdx.x & 63) << 1;   // feature pair base: 0,2,...,126
  const float di = dinv[node];
  float2 hv = *reinterpret_cast<const float2*>(&h[(size_t)node * FD + f2]);
  float accx = hv.x * di * di;
  float accy = hv.y * di * di;
  const int e0 = row_ptr[node], e1 = row_ptr[node + 1];
  for (int e = e0; e < e1; ++e) {
    int s   = csr_src[e];
    float c = csr_coef[e];
    float2 v = *reinterpret_cast<const float2*>(&h[(size_t)s * FD + f2]);
    accx += v.x * c;
    accy += v.y * c;
  }
  float2 o;
  o.x = fmaxf(accx + bias[f2],     0.f);
  o.y = fmaxf(accy + bias[f2 + 1], 0.f);
  *reinterpret_cast<float2*>(&out[(size_t)node * FD + f2]) = o;
}

// ---------------- launch ----------------

extern "C" void kernel_launch(void* const* d_in, const int* in_sizes, int n_in,
                              void* d_out, int out_size, void* d_ws, size_t ws_size,
                              hipStream_t stream) {
  const float* x  = (const float*)d_in[0];
  const float* W1 = (const float*)d_in[1];
  const float* b1 = (const float*)d_in[2];
  const float* W2 = (const float*)d_in[3];
  const float* b2 = (const float*)d_in[4];
  const float* Wf = (const float*)d_in[5];
  const float* bf = (const float*)d_in[6];
  const int*   ei = (const int*)d_in[7];

  const int N = in_sizes[0] / FD;
  const int E = in_sizes[7] / 2;
  const int O = in_sizes[6];
  const int* src = ei;
  const int* dst = ei + E;

  char* ws = (char*)d_ws;
  size_t off = 0;
  auto alloc = [&](size_t bytes) -> void* {
    void* p = ws + off;
    off += (bytes + 255) & ~(size_t)255;
    return p;
  };
  float* A        = (float*)alloc((size_t)N * FD * 4);
  float* B        = (float*)alloc((size_t)N * FD * 4);
  int*   deg      = (int*)  alloc((size_t)N * 4);
  float* dinv     = (float*)alloc((size_t)N * 4);
  int*   row_ptr  = (int*)  alloc((size_t)(N + 1) * 4);
  int*   cursor   = (int*)  alloc((size_t)N * 4);
  int*   csr_src  = (int*)  alloc((size_t)E * 4);
  float* csr_coef = (float*)alloc((size_t)E * 4);

  hipMemsetAsync(deg, 0, (size_t)N * 4, stream);
  k_deg <<<(E + 255) / 256, 256, 0, stream>>>(dst, deg, E);
  k_dinv<<<(N + 255) / 256, 256, 0, stream>>>(deg, dinv, N);
  k_scan<<<1, 1024, 0, stream>>>(deg, row_ptr, cursor, N);
  k_fill<<<(E + 255) / 256, 256, 0, stream>>>(src, dst, dinv, cursor, csr_src, csr_coef, E);

  const int gx = (N + 63) / 64;
  // layer 1: h = x@W1 ; agg+b1+relu
  k_gemm<<<dim3(gx, 2), 256, 0, stream>>>(x, W1, FD, nullptr, A, FD, N);
  k_agg <<<(N + 3) / 4, 256, 0, stream>>>(A, row_ptr, csr_src, csr_coef, dinv, b1, B, N);
  // layer 2
  k_gemm<<<dim3(gx, 2), 256, 0, stream>>>(B, W2, FD, nullptr, A, FD, N);
  k_agg <<<(N + 3) / 4, 256, 0, stream>>>(A, row_ptr, csr_src, csr_coef, dinv, b2, B, N);
  // final linear
  k_gemm<<<dim3(gx, 1), 256, 0, stream>>>(B, Wf, O, bf, (float*)d_out, O, N);
}

// Round 3
// 694.522 us; speedup vs baseline: 1.4409x; 1.4409x over previous
//
#include <hip/hip_runtime.h>

#define FD 128      // feature dim (D == H == 128)
#define SCAN_B 256  // blocks in hierarchical scan
#define SCAN_T 256  // threads per scan block

// ---------------- degree ----------------

__global__ void k_deg(const int* __restrict__ dst, int* __restrict__ deg, int E) {
  int e = blockIdx.x * blockDim.x + threadIdx.x;
  if (e < E) atomicAdd(&deg[dst[e]], 1);
}

// ---------------- hierarchical scan: partials (+ fused dinv) ----------------

__global__ __launch_bounds__(SCAN_T) void k_part(const int* __restrict__ deg,
                                                 float* __restrict__ dinv,
                                                 int* __restrict__ part, int n) {
  const int b = blockIdx.x;
  const int chunk = (n + SCAN_B - 1) / SCAN_B;
  const int lo = b * chunk;
  const int hi = min(lo + chunk, n);
  int sum = 0;
  for (int i = lo + threadIdx.x; i < hi; i += SCAN_T) {
    int d = deg[i];
    sum += d;
    dinv[i] = rsqrtf((float)(d + 1));   // +1 = self-loop
  }
  __shared__ int red[SCAN_T / 64];
  for (int off = 32; off > 0; off >>= 1) sum += __shfl_down(sum, off, 64);
  if ((threadIdx.x & 63) == 0) red[threadIdx.x >> 6] = sum;
  __syncthreads();
  if (threadIdx.x == 0) {
    int s = 0;
#pragma unroll
    for (int w = 0; w < SCAN_T / 64; ++w) s += red[w];
    part[b] = s;
  }
}

// single tiny block: exclusive scan of SCAN_B partials; writes row_ptr[n]=total
__global__ __launch_bounds__(SCAN_B) void k_scanpart(int* __restrict__ part,
                                                     int* __restrict__ row_ptr, int n) {
  __shared__ int s[SCAN_B];
  const int t = threadIdx.x;
  int v = part[t];
  s[t] = v;
  __syncthreads();
  for (int off = 1; off < SCAN_B; off <<= 1) {
    int u = (t >= off) ? s[t - off] : 0;
    __syncthreads();
    s[t] += u;
    __syncthreads();
  }
  part[t] = s[t] - v;                    // exclusive
  if (t == SCAN_B - 1) row_ptr[n] = s[t];
}

// per-block local scan -> row_ptr + cursor
__global__ __launch_bounds__(SCAN_T) void k_rowptr(const int* __restrict__ deg,
                                                   const int* __restrict__ part,
                                                   int* __restrict__ row_ptr,
                                                   int* __restrict__ cursor, int n) {
  const int b = blockIdx.x;
  const int chunk = (n + SCAN_B - 1) / SCAN_B;
  const int lo = b * chunk;
  const int hi = min(lo + chunk, n);
  const int sub = (chunk + SCAN_T - 1) / SCAN_T;
  const int t = threadIdx.x;
  const int slo = min(lo + t * sub, hi);
  const int shi = min(slo + sub, hi);
  int sum = 0;
  for (int i = slo; i < shi; ++i) sum += deg[i];
  __shared__ int s[SCAN_T];
  s[t] = sum;
  __syncthreads();
  for (int off = 1; off < SCAN_T; off <<= 1) {
    int u = (t >= off) ? s[t - off] : 0;
    __syncthreads();
    s[t] += u;
    __syncthreads();
  }
  int run = part[b] + s[t] - sum;        // global exclusive prefix for this thread
  for (int i = slo; i < shi; ++i) {
    row_ptr[i] = run;
    cursor[i]  = run;
    run += deg[i];
  }
}

// ---------------- CSR fill ----------------

__global__ void k_fill(const int* __restrict__ src, const int* __restrict__ dst,
                       const float* __restrict__ dinv, int* __restrict__ cursor,
                       int* __restrict__ csr_src, float* __restrict__ csr_coef, int E) {
  int e = blockIdx.x * blockDim.x + threadIdx.x;
  if (e < E) {
    int s = src[e], d = dst[e];
    int pos = atomicAdd(&cursor[d], 1);
    csr_src[pos]  = s;
    csr_coef[pos] = dinv[s] * dinv[d];
  }
}

// ---------------- f32 GEMM: out[r][c0+c] = sum_k A[r][k]*W[k][c0+c] (+bias) ----------------
// 64 rows x 64 cols per block, 256 threads, K=128 staged in two 64-row halves of W.

__global__ __launch_bounds__(256) void k_gemm(const float* __restrict__ A,
                                              const float* __restrict__ W, int ldw,
                                              const float* __restrict__ bias,
                                              float* __restrict__ out, int ldo, int nrows) {
  __shared__ float Ws[64 * 64];
  __shared__ float xs[64][129];   // bank = (r + k) % 32 -> conflict-free column reads
  const int t  = threadIdx.x;
  const int c0 = blockIdx.y * 64;
  const int r0 = blockIdx.x * 64;

  for (int i = t; i < 64 * 32; i += 256) {
    int r  = i >> 5;
    int k4 = (i & 31) << 2;
    int row = r0 + r;
    float4 v = make_float4(0.f, 0.f, 0.f, 0.f);
    if (row < nrows) v = *reinterpret_cast<const float4*>(&A[(size_t)row * FD + k4]);
    xs[r][k4 + 0] = v.x; xs[r][k4 + 1] = v.y; xs[r][k4 + 2] = v.z; xs[r][k4 + 3] = v.w;
  }

  const int r  = t & 31;
  const int cb = (t >> 5) << 3;
  float acc0[8], acc1[8];
#pragma unroll
  for (int j = 0; j < 8; ++j) {
    float bz = bias ? bias[c0 + cb + j] : 0.f;
    acc0[j] = bz; acc1[j] = bz;
  }

  for (int half = 0; half < 2; ++half) {
    __syncthreads();
    for (int i = t; i < 64 * 16; i += 256) {
      int k  = i >> 4;
      int c4 = (i & 15) << 2;
      *reinterpret_cast<float4*>(&Ws[k * 64 + c4]) =
          *reinterpret_cast<const float4*>(&W[(size_t)(half * 64 + k) * ldw + c0 + c4]);
    }
    __syncthreads();
    const int kbase = half * 64;
#pragma unroll 8
    for (int k = 0; k < 64; ++k) {
      float x0 = xs[r][kbase + k];
      float x1 = xs[r + 32][kbase + k];
      const float4 w0 = *reinterpret_cast<const float4*>(&Ws[k * 64 + cb]);
      const float4 w1 = *reinterpret_cast<const float4*>(&Ws[k * 64 + cb + 4]);
      acc0[0] += x0 * w0.x; acc0[1] += x0 * w0.y; acc0[2] += x0 * w0.z; acc0[3] += x0 * w0.w;
      acc0[4] += x0 * w1.x; acc0[5] += x0 * w1.y; acc0[6] += x0 * w1.z; acc0[7] += x0 * w1.w;
      acc1[0] += x1 * w0.x; acc1[1] += x1 * w0.y; acc1[2] += x1 * w0.z; acc1[3] += x1 * w0.w;
      acc1[4] += x1 * w1.x; acc1[5] += x1 * w1.y; acc1[6] += x1 * w1.z; acc1[7] += x1 * w1.w;
    }
  }

  const int row0 = r0 + r, row1 = r0 + r + 32;
  if (row0 < nrows) {
    float* o = &out[(size_t)row0 * ldo + c0 + cb];
    *reinterpret_cast<float4*>(o)     = make_float4(acc0[0], acc0[1], acc0[2], acc0[3]);
    *reinterpret_cast<float4*>(o + 4) = make_float4(acc0[4], acc0[5], acc0[6], acc0[7]);
  }
  if (row1 < nrows) {
    float* o = &out[(size_t)row1 * ldo + c0 + cb];
    *reinterpret_cast<float4*>(o)     = make_float4(acc1[0], acc1[1], acc1[2], acc1[3]);
    *reinterpret_cast<float4*>(o + 4) = make_float4(acc1[4], acc1[5], acc1[6], acc1[7]);
  }
}

// ---------------- aggregation: out[n] = relu( sum_in h[s]*coef + h[n]*dinv^2 + b ) ----------------
// one 64-lane wave per node, float2 per lane; 4 nodes per 256-thread block; 2-edge unroll for ILP

__global__ __launch_bounds__(256) void k_agg(const float* __restrict__ h,
                                             const int* __restrict__ row_ptr,
                                             const int* __restrict__ csr_src,
                                             const float* __restrict__ csr_coef,
                                             const float* __restrict__ dinv,
                                             const float* __restrict__ bias,
                                             float* __restrict__ out, int n) {
  const int node = blockIdx.x * 4 + (threadIdx.x >> 6);
  if (node >= n) return;
  const int f2 = (threadIdx.x & 63) << 1;
  const float di = dinv[node];
  float2 hv = *reinterpret_cast<const float2*>(&h[(size_t)node * FD + f2]);
  float accx = hv.x * di * di;
  float accy = hv.y * di * di;
  const int e0 = row_ptr[node], e1 = row_ptr[node + 1];
  int e = e0;
  for (; e + 2 <= e1; e += 2) {
    int s0   = csr_src[e];
    int s1   = csr_src[e + 1];
    float c0 = csr_coef[e];
    float c1 = csr_coef[e + 1];
    float2 v0 = *reinterpret_cast<const float2*>(&h[(size_t)s0 * FD + f2]);
    float2 v1 = *reinterpret_cast<const float2*>(&h[(size_t)s1 * FD + f2]);
    accx += v0.x * c0; accy += v0.y * c0;
    accx += v1.x * c1; accy += v1.y * c1;
  }
  if (e < e1) {
    int s   = csr_src[e];
    float c = csr_coef[e];
    float2 v = *reinterpret_cast<const float2*>(&h[(size_t)s * FD + f2]);
    accx += v.x * c; accy += v.y * c;
  }
  float2 o;
  o.x = fmaxf(accx + bias[f2],     0.f);
  o.y = fmaxf(accy + bias[f2 + 1], 0.f);
  *reinterpret_cast<float2*>(&out[(size_t)node * FD + f2]) = o;
}

// ---------------- launch ----------------

extern "C" void kernel_launch(void* const* d_in, const int* in_sizes, int n_in,
                              void* d_out, int out_size, void* d_ws, size_t ws_size,
                              hipStream_t stream) {
  const float* x  = (const float*)d_in[0];
  const float* W1 = (const float*)d_in[1];
  const float* b1 = (const float*)d_in[2];
  const float* W2 = (const float*)d_in[3];
  const float* b2 = (const float*)d_in[4];
  const float* Wf = (const float*)d_in[5];
  const float* bf = (const float*)d_in[6];
  const int*   ei = (const int*)d_in[7];

  const int N = in_sizes[0] / FD;
  const int E = in_sizes[7] / 2;
  const int O = in_sizes[6];
  const int* src = ei;
  const int* dst = ei + E;

  char* ws = (char*)d_ws;
  size_t off = 0;
  auto alloc = [&](size_t bytes) -> void* {
    void* p = ws + off;
    off += (bytes + 255) & ~(size_t)255;
    return p;
  };
  float* A        = (float*)alloc((size_t)N * FD * 4);
  float* B        = (float*)alloc((size_t)N * FD * 4);
  int*   deg      = (int*)  alloc((size_t)N * 4);
  float* dinv     = (float*)alloc((size_t)N * 4);
  int*   row_ptr  = (int*)  alloc((size_t)(N + 1) * 4);
  int*   cursor   = (int*)  alloc((size_t)N * 4);
  int*   csr_src  = (int*)  alloc((size_t)E * 4);
  float* csr_coef = (float*)alloc((size_t)E * 4);
  int*   part     = (int*)  alloc((size_t)SCAN_B * 4);

  hipMemsetAsync(deg, 0, (size_t)N * 4, stream);
  k_deg     <<<(E + 255) / 256, 256, 0, stream>>>(dst, deg, E);
  k_part    <<<SCAN_B, SCAN_T, 0, stream>>>(deg, dinv, part, N);
  k_scanpart<<<1, SCAN_B, 0, stream>>>(part, row_ptr, N);
  k_rowptr  <<<SCAN_B, SCAN_T, 0, stream>>>(deg, part, row_ptr, cursor, N);
  k_fill    <<<(E + 255) / 256, 256, 0, stream>>>(src, dst, dinv, cursor, csr_src, csr_coef, E);

  const int gx = (N + 63) / 64;
  // layer 1: h = x@W1 ; agg+b1+relu
  k_gemm<<<dim3(gx, 2), 256, 0, stream>>>(x, W1, FD, nullptr, A, FD, N);
  k_agg <<<(N + 3) / 4, 256, 0, stream>>>(A, row_ptr, csr_src, csr_coef, dinv, b1, B, N);
  // layer 2
  k_gemm<<<dim3(gx, 2), 256, 0, stream>>>(B, W2, FD, nullptr, A, FD, N);
  k_agg <<<(N + 3) / 4, 256, 0, stream>>>(A, row_ptr, csr_src, csr_coef, dinv, b2, B, N);
  // final linear
  k_gemm<<<dim3(gx, 1), 256, 0, stream>>>(B, Wf, O, bf, (float*)d_out, O, N);
}

// Round 4
// 643.309 us; speedup vs baseline: 1.5556x; 1.0796x over previous
//
#include <hip/hip_runtime.h>

#define FD 128      // feature dim (D == H == 128)
#define SCAN_B 256  // blocks in hierarchical scan
#define SCAN_T 256  // threads per scan block

// ---------------- degree ----------------

__global__ void k_deg(const int* __restrict__ dst, int* __restrict__ deg, int E) {
  int e = blockIdx.x * blockDim.x + threadIdx.x;
  if (e < E) atomicAdd(&deg[dst[e]], 1);
}

// ---------------- hierarchical scan: partials (+ fused dinv) ----------------

__global__ __launch_bounds__(SCAN_T) void k_part(const int* __restrict__ deg,
                                                 float* __restrict__ dinv,
                                                 int* __restrict__ part, int n) {
  const int b = blockIdx.x;
  const int chunk = (n + SCAN_B - 1) / SCAN_B;
  const int lo = b * chunk;
  const int hi = min(lo + chunk, n);
  int sum = 0;
  for (int i = lo + threadIdx.x; i < hi; i += SCAN_T) {
    int d = deg[i];
    sum += d;
    dinv[i] = rsqrtf((float)(d + 1));   // +1 = self-loop
  }
  __shared__ int red[SCAN_T / 64];
  for (int off = 32; off > 0; off >>= 1) sum += __shfl_down(sum, off, 64);
  if ((threadIdx.x & 63) == 0) red[threadIdx.x >> 6] = sum;
  __syncthreads();
  if (threadIdx.x == 0) {
    int s = 0;
#pragma unroll
    for (int w = 0; w < SCAN_T / 64; ++w) s += red[w];
    part[b] = s;
  }
}

__global__ __launch_bounds__(SCAN_B) void k_scanpart(int* __restrict__ part,
                                                     int* __restrict__ row_ptr, int n) {
  __shared__ int s[SCAN_B];
  const int t = threadIdx.x;
  int v = part[t];
  s[t] = v;
  __syncthreads();
  for (int off = 1; off < SCAN_B; off <<= 1) {
    int u = (t >= off) ? s[t - off] : 0;
    __syncthreads();
    s[t] += u;
    __syncthreads();
  }
  part[t] = s[t] - v;                    // exclusive
  if (t == SCAN_B - 1) row_ptr[n] = s[t];
}

__global__ __launch_bounds__(SCAN_T) void k_rowptr(const int* __restrict__ deg,
                                                   const int* __restrict__ part,
                                                   int* __restrict__ row_ptr,
                                                   int* __restrict__ cursor, int n) {
  const int b = blockIdx.x;
  const int chunk = (n + SCAN_B - 1) / SCAN_B;
  const int lo = b * chunk;
  const int hi = min(lo + chunk, n);
  const int sub = (chunk + SCAN_T - 1) / SCAN_T;
  const int t = threadIdx.x;
  const int slo = min(lo + t * sub, hi);
  const int shi = min(slo + sub, hi);
  int sum = 0;
  for (int i = slo; i < shi; ++i) sum += deg[i];
  __shared__ int s[SCAN_T];
  s[t] = sum;
  __syncthreads();
  for (int off = 1; off < SCAN_T; off <<= 1) {
    int u = (t >= off) ? s[t - off] : 0;
    __syncthreads();
    s[t] += u;
    __syncthreads();
  }
  int run = part[b] + s[t] - sum;
  for (int i = slo; i < shi; ++i) {
    row_ptr[i] = run;
    cursor[i]  = run;
    run += deg[i];
  }
}

// ---------------- CSR fill: one interleaved {src, coef} record per edge ----------------

__global__ void k_fill(const int* __restrict__ src, const int* __restrict__ dst,
                       const float* __restrict__ dinv, int* __restrict__ cursor,
                       int2* __restrict__ csr, int E) {
  int e = blockIdx.x * blockDim.x + threadIdx.x;
  if (e < E) {
    int s = src[e], d = dst[e];
    int pos = atomicAdd(&cursor[d], 1);
    csr[pos] = make_int2(s, __float_as_int(dinv[s] * dinv[d]));
  }
}

// ---------------- f32 GEMM: out = A @ W (+bias), 128 rows x 64 cols per block ----------------
// 256 threads, 32 accs/thread (4 rows x 8 cols). x staged k-major so both LDS
// operands read as ds_read_b128; per-k per-wave LDS ~36cy < VALU 64cy -> VALU-bound.

__global__ __launch_bounds__(256) void k_gemm(const float* __restrict__ A, int lda,
                                              const float* __restrict__ W, int ldw,
                                              const float* __restrict__ bias,
                                              float* __restrict__ out, int ldo, int nrows) {
  __shared__ float Ws[64 * 64];     // 16 KB: W rows [kbase,kbase+64) x 64 cols
  __shared__ float xsT[64 * 128];   // 32 KB: k-major x: xsT[k][r]
  const int t  = threadIdx.x;
  const int c0 = blockIdx.y * 64;
  const int r0 = blockIdx.x * 128;

  const int rgrp = t & 31;          // row quad: rows rgrp*4 .. rgrp*4+3
  const int cgrp = t >> 5;          // 8 col-groups of 8

  float acc[4][8];
#pragma unroll
  for (int i = 0; i < 4; ++i)
#pragma unroll
    for (int j = 0; j < 8; ++j)
      acc[i][j] = bias ? bias[c0 + cgrp * 8 + j] : 0.f;

  const int rr = t & 127;           // staging: row within tile
  const int hk = t >> 7;            // staging: k-half (0/1) of the 64-k panel

  for (int half = 0; half < 2; ++half) {
    const int kbase = half * 64;
    __syncthreads();                 // protect LDS reuse across halves
    // stage W panel
    for (int i = t; i < 64 * 16; i += 256) {
      int k  = i >> 4;
      int c4 = (i & 15) << 2;
      *reinterpret_cast<float4*>(&Ws[k * 64 + c4]) =
          *reinterpret_cast<const float4*>(&W[(size_t)(kbase + k) * ldw + c0 + c4]);
    }
    // stage x panel transposed: thread reads one 128B row-chunk, writes 32 b32 (lanes contiguous in r)
    {
      const int row = r0 + rr;
      const float* ap = &A[(size_t)row * lda + kbase + hk * 32];
#pragma unroll
      for (int j = 0; j < 8; ++j) {
        float4 v = make_float4(0.f, 0.f, 0.f, 0.f);
        if (row < nrows) v = *reinterpret_cast<const float4*>(ap + j * 4);
        const int kb = hk * 32 + j * 4;
        xsT[(kb + 0) * 128 + rr] = v.x;
        xsT[(kb + 1) * 128 + rr] = v.y;
        xsT[(kb + 2) * 128 + rr] = v.z;
        xsT[(kb + 3) * 128 + rr] = v.w;
      }
    }
    __syncthreads();
#pragma unroll 4
    for (int k = 0; k < 64; ++k) {
      const float4 xv = *reinterpret_cast<const float4*>(&xsT[k * 128 + rgrp * 4]);
      const float4 w0 = *reinterpret_cast<const float4*>(&Ws[k * 64 + cgrp * 8]);
      const float4 w1 = *reinterpret_cast<const float4*>(&Ws[k * 64 + cgrp * 8 + 4]);
      const float x[4] = {xv.x, xv.y, xv.z, xv.w};
      const float w[8] = {w0.x, w0.y, w0.z, w0.w, w1.x, w1.y, w1.z, w1.w};
#pragma unroll
      for (int i = 0; i < 4; ++i)
#pragma unroll
        for (int j = 0; j < 8; ++j)
          acc[i][j] += x[i] * w[j];
    }
  }

#pragma unroll
  for (int i = 0; i < 4; ++i) {
    const int row = r0 + rgrp * 4 + i;
    if (row < nrows) {
      float* o = &out[(size_t)row * ldo + c0 + cgrp * 8];
      *reinterpret_cast<float4*>(o)     = make_float4(acc[i][0], acc[i][1], acc[i][2], acc[i][3]);
      *reinterpret_cast<float4*>(o + 4) = make_float4(acc[i][4], acc[i][5], acc[i][6], acc[i][7]);
    }
  }
}

// ---------------- aggregation: out[n] = relu( sum_in h[s]*coef + h[n]*dinv^2 + b ) ----------------
// one 64-lane wave per node, float2 per lane; unroll-4 edge loop -> 4 gathers in flight

__global__ __launch_bounds__(256) void k_agg(const float* __restrict__ h,
                                             const int* __restrict__ row_ptr,
                                             const int2* __restrict__ csr,
                                             const float* __restrict__ dinv,
                                             const float* __restrict__ bias,
                                             float* __restrict__ out, int n) {
  const int node = blockIdx.x * 4 + (threadIdx.x >> 6);
  if (node >= n) return;
  const int f2 = (threadIdx.x & 63) << 1;
  const float di = dinv[node];
  float2 hv = *reinterpret_cast<const float2*>(&h[(size_t)node * FD + f2]);
  float accx = hv.x * di * di;
  float accy = hv.y * di * di;
  const int e0 = row_ptr[node], e1 = row_ptr[node + 1];
  int e = e0;
  for (; e + 4 <= e1; e += 4) {
    const int2 E0 = csr[e];
    const int2 E1 = csr[e + 1];
    const int2 E2 = csr[e + 2];
    const int2 E3 = csr[e + 3];
    const float2 v0 = *reinterpret_cast<const float2*>(&h[(size_t)E0.x * FD + f2]);
    const float2 v1 = *reinterpret_cast<const float2*>(&h[(size_t)E1.x * FD + f2]);
    const float2 v2 = *reinterpret_cast<const float2*>(&h[(size_t)E2.x * FD + f2]);
    const float2 v3 = *reinterpret_cast<const float2*>(&h[(size_t)E3.x * FD + f2]);
    const float c0 = __int_as_float(E0.y);
    const float c1 = __int_as_float(E1.y);
    const float c2 = __int_as_float(E2.y);
    const float c3 = __int_as_float(E3.y);
    accx += v0.x * c0; accy += v0.y * c0;
    accx += v1.x * c1; accy += v1.y * c1;
    accx += v2.x * c2; accy += v2.y * c2;
    accx += v3.x * c3; accy += v3.y * c3;
  }
  for (; e < e1; ++e) {
    const int2 E0 = csr[e];
    const float c = __int_as_float(E0.y);
    const float2 v = *reinterpret_cast<const float2*>(&h[(size_t)E0.x * FD + f2]);
    accx += v.x * c; accy += v.y * c;
  }
  float2 o;
  o.x = fmaxf(accx + bias[f2],     0.f);
  o.y = fmaxf(accy + bias[f2 + 1], 0.f);
  *reinterpret_cast<float2*>(&out[(size_t)node * FD + f2]) = o;
}

// ---------------- launch ----------------

extern "C" void kernel_launch(void* const* d_in, const int* in_sizes, int n_in,
                              void* d_out, int out_size, void* d_ws, size_t ws_size,
                              hipStream_t stream) {
  const float* x  = (const float*)d_in[0];
  const float* W1 = (const float*)d_in[1];
  const float* b1 = (const float*)d_in[2];
  const float* W2 = (const float*)d_in[3];
  const float* b2 = (const float*)d_in[4];
  const float* Wf = (const float*)d_in[5];
  const float* bf = (const float*)d_in[6];
  const int*   ei = (const int*)d_in[7];

  const int N = in_sizes[0] / FD;
  const int E = in_sizes[7] / 2;
  const int O = in_sizes[6];
  const int* src = ei;
  const int* dst = ei + E;

  char* ws = (char*)d_ws;
  size_t off = 0;
  auto alloc = [&](size_t bytes) -> void* {
    void* p = ws + off;
    off += (bytes + 255) & ~(size_t)255;
    return p;
  };
  float* A       = (float*)alloc((size_t)N * FD * 4);
  float* B       = (float*)alloc((size_t)N * FD * 4);
  int*   deg     = (int*)  alloc((size_t)N * 4);
  float* dinv    = (float*)alloc((size_t)N * 4);
  int*   row_ptr = (int*)  alloc((size_t)(N + 1) * 4);
  int*   cursor  = (int*)  alloc((size_t)N * 4);
  int2*  csr     = (int2*) alloc((size_t)E * 8);
  int*   part    = (int*)  alloc((size_t)SCAN_B * 4);

  hipMemsetAsync(deg, 0, (size_t)N * 4, stream);
  k_deg     <<<(E + 255) / 256, 256, 0, stream>>>(dst, deg, E);
  k_part    <<<SCAN_B, SCAN_T, 0, stream>>>(deg, dinv, part, N);
  k_scanpart<<<1, SCAN_B, 0, stream>>>(part, row_ptr, N);
  k_rowptr  <<<SCAN_B, SCAN_T, 0, stream>>>(deg, part, row_ptr, cursor, N);
  k_fill    <<<(E + 255) / 256, 256, 0, stream>>>(src, dst, dinv, cursor, csr, E);

  const int gx = (N + 127) / 128;
  // layer 1: h = x@W1 ; agg+b1+relu
  k_gemm<<<dim3(gx, 2), 256, 0, stream>>>(x, FD, W1, FD, nullptr, A, FD, N);
  k_agg <<<(N + 3) / 4, 256, 0, stream>>>(A, row_ptr, csr, dinv, b1, B, N);
  // layer 2
  k_gemm<<<dim3(gx, 2), 256, 0, stream>>>(B, FD, W2, FD, nullptr, A, FD, N);
  k_agg <<<(N + 3) / 4, 256, 0, stream>>>(A, row_ptr, csr, dinv, b2, B, N);
  // final linear
  k_gemm<<<dim3(gx, 1), 256, 0, stream>>>(B, FD, Wf, O, bf, (float*)d_out, O, N);
}